// Round 2
// baseline (770.424 us; speedup 1.0000x reference)
//
#include <hip/hip_runtime.h>
#include <math.h>

#define HW    (512 * 512)
#define FCH   64
#define NB    8
#define NID   32
#define CHUNK 2048
#define SUB   1024          // pixels per pipeline stage (4 KB)
#define NW    8             // waves per block

// async global->LDS, 16 B per lane (one wave-instruction = 1 KB)
__device__ __forceinline__ void glds16(const float* src, float* dst) {
    typedef __attribute__((address_space(1))) const void gvoid_t;
    typedef __attribute__((address_space(3))) void       lvoid_t;
    __builtin_amdgcn_global_load_lds((gvoid_t*)src, (lvoid_t*)dst, 16, 0, 0);
}

// stage SUB floats (4 KB) = 4 glds instructions
__device__ __forceinline__ void stage4(const float* gsrc, float* ldst, int lane) {
#pragma unroll
    for (int i = 0; i < 4; ++i)
        glds16(gsrc + i * 256 + lane * 4, ldst + i * 256);
}

// ---------------------------------------------------------------------------
// Kernel 1: per-instance segment max over encoded [B, F, H, W].
//
// Rounds 0/1 were LATENCY-bound: loads lived in VGPRs, so <=8 float4 in
// flight per wave => ~4 KB/CU in flight => ~2.8 TB/s ceiling (both rounds
// identical -- which is why restructuring LDS atomics was a null result).
//
// This version streams encoded through LDS with global_load_lds (vmcnt-
// tracked, no VGPR cost): each wave double-buffers 2 x 4 KB channel halves,
// 16 waves/CU x 4 KB => ~64 KB/CU in flight => HBM-bound.
//  - ids for the whole chunk live in registers (8 int4/lane, loaded once;
//    8x wave reuse of the same 8 KB is absorbed by L2).
//  - hot loop has NO vmem except the glds stream => vmcnt(0) waits are exact.
//  - per-wave private acc priv[33][4] (slot = id*4 + (lane&3)): collisions
//    need same id AND same lane-quad; bank spread exact (id%8 x 4).
//  - lgkmcnt(15) after each stage's 4 reads+16 atomics proves the buffer
//    being re-staged is fully read (its reads are older than the atomics).
//  - per-channel merged maxima parked in LDS res[][]; global atomics once
//    at block end (32 lanes x 8 channels per wave).
// LDS: 64 KB buf + 4.2 KB priv + 8 KB res = 76.1 KB -> 2 blocks/CU.
// ---------------------------------------------------------------------------
__global__ __launch_bounds__(512, 4) void segmax_kernel(
    const float* __restrict__ encoded,
    const int*   __restrict__ masks,
    float*       __restrict__ vectors)   // [B, NID, F], pre-zeroed
{
    const int b    = blockIdx.y;
    const int c0   = blockIdx.x * CHUNK;
    const int tid  = threadIdx.x;
    const int w    = tid >> 6;
    const int lane = tid & 63;
    const int g4   = lane & 3;

    __shared__ float buf[NW][2][SUB];      // 65536 B
    __shared__ float priv[NW][33 * 4];     //  4224 B
    __shared__ float res[NW][NID][8];      //  8192 B

    float*  pw  = priv[w];
    float4* pw4 = (float4*)pw;
    const float4 z4 = make_float4(0.f, 0.f, 0.f, 0.f);

    // ids for the whole chunk -> registers (8 int4 per lane, statically indexed)
    int4 id4[8];
    {
        const int4* msrc = (const int4*)(masks + (size_t)b * HW + c0);
#pragma unroll
        for (int it = 0; it < 8; ++it)
            id4[it] = msrc[it * 64 + lane];
    }

    // zero private accumulator (33 ids x 4 replicas)
    if (lane < 33) pw4[lane] = z4;
    asm volatile("s_waitcnt lgkmcnt(0)" ::: "memory");

    const float* ebase = encoded + ((size_t)b * FCH + w * 8) * HW + c0;

    // prologue: stage (c=0, h=0)
    stage4(ebase, buf[w][0], lane);

#pragma unroll
    for (int c = 0; c < 8; ++c) {
        const float* esrc = ebase + (size_t)c * HW;

        // ---- half 0: process buf0, then prefetch (c,1) into buf1
        asm volatile("s_waitcnt vmcnt(0)" ::: "memory");
#pragma unroll
        for (int i = 0; i < 4; ++i) {
            const float4 v  = ((const float4*)buf[w][0])[i * 64 + lane];
            const int4   id = id4[i];
            atomicMax((unsigned*)&pw[(id.x << 2) + g4], __float_as_uint(fmaxf(v.x, 0.f)));
            atomicMax((unsigned*)&pw[(id.y << 2) + g4], __float_as_uint(fmaxf(v.y, 0.f)));
            atomicMax((unsigned*)&pw[(id.z << 2) + g4], __float_as_uint(fmaxf(v.z, 0.f)));
            atomicMax((unsigned*)&pw[(id.w << 2) + g4], __float_as_uint(fmaxf(v.w, 0.f)));
        }
        asm volatile("s_waitcnt lgkmcnt(15)" ::: "memory");  // buf0 reads serviced
        stage4(esrc + SUB, buf[w][1], lane);

        // ---- half 1: process buf1, then prefetch (c+1,0) into buf0
        asm volatile("s_waitcnt vmcnt(0)" ::: "memory");
#pragma unroll
        for (int i = 0; i < 4; ++i) {
            const float4 v  = ((const float4*)buf[w][1])[i * 64 + lane];
            const int4   id = id4[4 + i];
            atomicMax((unsigned*)&pw[(id.x << 2) + g4], __float_as_uint(fmaxf(v.x, 0.f)));
            atomicMax((unsigned*)&pw[(id.y << 2) + g4], __float_as_uint(fmaxf(v.y, 0.f)));
            atomicMax((unsigned*)&pw[(id.z << 2) + g4], __float_as_uint(fmaxf(v.z, 0.f)));
            atomicMax((unsigned*)&pw[(id.w << 2) + g4], __float_as_uint(fmaxf(v.w, 0.f)));
        }
        asm volatile("s_waitcnt lgkmcnt(15)" ::: "memory");  // buf1 reads serviced
        if (c < 7)
            stage4(esrc + HW, buf[w][0], lane);

        // ---- merge channel c into res (LDS only -- no vmem, prefetch unaffected)
        asm volatile("s_waitcnt lgkmcnt(0)" ::: "memory");   // atomics drained
        if (lane < NID) {
            const float4 m4 = pw4[lane + 1];
            res[w][lane][c] = fmaxf(fmaxf(m4.x, m4.y), fmaxf(m4.z, m4.w));
        }
        if (lane < 33) pw4[lane] = z4;                        // re-zero (same-wave DS order)
        asm volatile("s_waitcnt lgkmcnt(0)" ::: "memory");
    }

    // epilogue: one global atomic per (id, channel)
    if (lane < NID) {
        const float4 r0 = *(const float4*)&res[w][lane][0];
        const float4 r1 = *(const float4*)&res[w][lane][4];
        float* vd = vectors + ((size_t)b * NID + lane) * FCH + w * 8;
        if (r0.x > 0.f) atomicMax((unsigned*)&vd[0], __float_as_uint(r0.x));
        if (r0.y > 0.f) atomicMax((unsigned*)&vd[1], __float_as_uint(r0.y));
        if (r0.z > 0.f) atomicMax((unsigned*)&vd[2], __float_as_uint(r0.z));
        if (r0.w > 0.f) atomicMax((unsigned*)&vd[3], __float_as_uint(r0.w));
        if (r1.x > 0.f) atomicMax((unsigned*)&vd[4], __float_as_uint(r1.x));
        if (r1.y > 0.f) atomicMax((unsigned*)&vd[5], __float_as_uint(r1.y));
        if (r1.z > 0.f) atomicMax((unsigned*)&vd[6], __float_as_uint(r1.z));
        if (r1.w > 0.f) atomicMax((unsigned*)&vd[7], __float_as_uint(r1.w));
    }
}

// ---------------------------------------------------------------------------
// Kernel 2: collapsed pairwise MLP (no nonlinearity between layers):
// out[b,i,j,c] = sigmoid(v_i·A[:,c] + v_j·B[:,c] + cc[c]),
// A = w1[:64]@w2, B = w1[64:]@w2, cc = b1@w2 + b2.
// connections[b, c, j, i] = out[b, i, j, c].      (~5 us, unchanged)
// ---------------------------------------------------------------------------
__global__ __launch_bounds__(256) void conn_kernel(
    const float* __restrict__ vectors,  // [B, NID, F]
    const float* __restrict__ w1,       // [128, 32]
    const float* __restrict__ b1,       // [32]
    const float* __restrict__ w2,       // [32, 4]
    const float* __restrict__ b2,       // [4]
    float*       __restrict__ out)      // [B, 4, NID, NID]
{
    const int b   = blockIdx.x;
    const int tid = threadIdx.x;

    __shared__ float v[NID][FCH];
    __shared__ float A[FCH][4], Bm[FCH][4];
    __shared__ float s[NID][4], t[NID][4];
    __shared__ float cc[4];

    for (int i = tid; i < NID * FCH; i += 256)
        ((float*)v)[i] = vectors[(size_t)b * NID * FCH + i];

    {
        const int k = tid >> 2, c = tid & 3;
        float a = 0.0f, bb = 0.0f;
#pragma unroll
        for (int h = 0; h < 32; ++h) {
            const float w2v = w2[h * 4 + c];
            a  += w1[k * 32 + h]        * w2v;
            bb += w1[(k + 64) * 32 + h] * w2v;
        }
        A[k][c]  = a;
        Bm[k][c] = bb;
        if (tid < 4) {
            float x = b2[tid];
#pragma unroll
            for (int h = 0; h < 32; ++h) x += b1[h] * w2[h * 4 + tid];
            cc[tid] = x;
        }
    }
    __syncthreads();

    if (tid < 128) {
        const int i = tid >> 2, c = tid & 3;
        float a = 0.0f;
#pragma unroll
        for (int f = 0; f < FCH; ++f) a += v[i][f] * A[f][c];
        s[i][c] = a;
    } else {
        const int j = (tid - 128) >> 2, c = tid & 3;
        float a = 0.0f;
#pragma unroll
        for (int f = 0; f < FCH; ++f) a += v[j][f] * Bm[f][c];
        t[j][c] = a;
    }
    __syncthreads();

    for (int o = tid; o < 4 * NID * NID; o += 256) {
        const int i = o & 31;
        const int j = (o >> 5) & 31;
        const int c = o >> 10;
        const float x = s[i][c] + t[j][c] + cc[c];
        out[(((size_t)b * 4 + c) * NID + j) * NID + i] = 1.0f / (1.0f + expf(-x));
    }
}

extern "C" void kernel_launch(void* const* d_in, const int* in_sizes, int n_in,
                              void* d_out, int out_size, void* d_ws, size_t ws_size,
                              hipStream_t stream) {
    const float* encoded = (const float*)d_in[0];
    const int*   masks   = (const int*)d_in[1];
    const float* w1      = (const float*)d_in[2];
    const float* b1      = (const float*)d_in[3];
    const float* w2      = (const float*)d_in[4];
    const float* b2      = (const float*)d_in[5];
    float* out = (float*)d_out;

    float* vectors     = out;                        // NB*NID*FCH = 16384 floats
    float* connections = out + NB * NID * FCH;       // NB*4*NID*NID = 32768 floats

    // vectors must start at 0 (uint-monotone atomicMax; absent id -> 0)
    hipMemsetAsync(vectors, 0, (size_t)NB * NID * FCH * sizeof(float), stream);

    segmax_kernel<<<dim3(HW / CHUNK, NB), 512, 0, stream>>>(encoded, masks, vectors);
    conn_kernel<<<NB, 256, 0, stream>>>(vectors, w1, b1, w2, b2, connections);
}

// Round 3
// 765.987 us; speedup vs baseline: 1.0058x; 1.0058x over previous
//
#include <hip/hip_runtime.h>
#include <math.h>

#define HW    (512 * 512)
#define FCH   64
#define NB    8
#define NID   32
#define CHUNK 2048
#define SUB   1024          // pixels per pipeline stage (4 KB)
#define NW    8             // waves per block

// async global->LDS, 16 B per lane (one wave-instruction = 1 KB)
__device__ __forceinline__ void glds16(const float* src, float* dst) {
    typedef __attribute__((address_space(1))) const void gvoid_t;
    typedef __attribute__((address_space(3))) void       lvoid_t;
    __builtin_amdgcn_global_load_lds((gvoid_t*)src, (lvoid_t*)dst, 16, 0, 0);
}

// stage SUB floats (4 KB) = 4 glds instructions
__device__ __forceinline__ void stage4(const float* gsrc, float* ldst, int lane) {
#pragma unroll
    for (int i = 0; i < 4; ++i)
        glds16(gsrc + i * 256 + lane * 4, ldst + i * 256);
}

// ---------------------------------------------------------------------------
// Kernel 1: per-instance segment max over encoded [B, F, H, W].
//
// Round-2 post-mortem: the glds double-buffer used s_waitcnt vmcnt(0) at the
// top of each half, which drains the JUST-ISSUED prefetch too -> zero overlap,
// every 4 KB stage exposed full HBM latency (770 us total, +45 regression).
//
// This round keeps the structure and fixes the waits (T4: counted vmcnt):
//  - steady state: 8 glds in flight (2 stages); vmcnt(4) releases the older
//    stage while the newer one keeps flying; vmcnt(0) only on the last stage.
//  - lgkmcnt(4) after processing a buffer proves its 4 ds_read_b128 retired
//    (each atomic depends on its read, so reads are among the oldest 16 of
//    the 20 DS ops) before the buffer is re-staged.
//  - prologue vmcnt(0) after the mask loads so in-loop vmcnt counts are exact
//    (the glds stream is the only vmem in the loop).
//  - channel merge is LDS-only: lgkmcnt(0) drains atomics without touching
//    vmcnt -> prefetch unaffected.
// 16 waves/CU x 4-8 KB in flight ~ 64-128 KB/CU / ~900 cy  >>  24.6 GB/s/CU
// needed for HBM saturation -> BW-bound (~520 MB -> ~90-110 us).
// LDS: 64 KB buf + 4.2 KB priv + 8 KB res = 76.1 KB -> 2 blocks/CU.
// ---------------------------------------------------------------------------
__global__ __launch_bounds__(512, 4) void segmax_kernel(
    const float* __restrict__ encoded,
    const int*   __restrict__ masks,
    float*       __restrict__ vectors)   // [B, NID, F], pre-zeroed
{
    const int b    = blockIdx.y;
    const int c0   = blockIdx.x * CHUNK;
    const int tid  = threadIdx.x;
    const int w    = tid >> 6;
    const int lane = tid & 63;
    const int g4   = lane & 3;

    __shared__ float buf[NW][2][SUB];      // 65536 B
    __shared__ float priv[NW][33 * 4];     //  4224 B
    __shared__ float res[NW][NID][8];      //  8192 B

    float*  pw  = priv[w];
    float4* pw4 = (float4*)pw;
    const float4 z4 = make_float4(0.f, 0.f, 0.f, 0.f);

    // ids for the whole chunk -> registers (8 int4 per lane, statically indexed)
    int4 id4[8];
    {
        const int4* msrc = (const int4*)(masks + (size_t)b * HW + c0);
#pragma unroll
        for (int it = 0; it < 8; ++it)
            id4[it] = msrc[it * 64 + lane];
    }
    // drain mask loads so the in-loop vmcnt counts are exact
    asm volatile("s_waitcnt vmcnt(0)" ::: "memory");

    // zero private accumulator (33 ids x 4 replicas)
    if (lane < 33) pw4[lane] = z4;
    asm volatile("s_waitcnt lgkmcnt(0)" ::: "memory");

    const float* ebase = encoded + ((size_t)b * FCH + w * 8) * HW + c0;

    // prologue: 2 stages in flight
    stage4(ebase,       buf[w][0], lane);   // stage 0 (c=0, half 0)
    stage4(ebase + SUB, buf[w][1], lane);   // stage 1 (c=0, half 1)

#pragma unroll 8
    for (int c = 0; c < 8; ++c) {
        const float* esrc = ebase + (size_t)c * HW;

        // ---- half 0: buf0 holds stage 2c; stage 2c+1 still in flight
        asm volatile("s_waitcnt vmcnt(4)" ::: "memory");
#pragma unroll
        for (int i = 0; i < 4; ++i) {
            const float4 v  = ((const float4*)buf[w][0])[i * 64 + lane];
            const int4   id = id4[i];
            atomicMax((unsigned*)&pw[(id.x << 2) + g4], __float_as_uint(fmaxf(v.x, 0.f)));
            atomicMax((unsigned*)&pw[(id.y << 2) + g4], __float_as_uint(fmaxf(v.y, 0.f)));
            atomicMax((unsigned*)&pw[(id.z << 2) + g4], __float_as_uint(fmaxf(v.z, 0.f)));
            atomicMax((unsigned*)&pw[(id.w << 2) + g4], __float_as_uint(fmaxf(v.w, 0.f)));
        }
        asm volatile("s_waitcnt lgkmcnt(4)" ::: "memory");   // buf0 reads retired
        if (c < 7)
            stage4(esrc + HW, buf[w][0], lane);              // stage 2c+2

        // ---- half 1: buf1 holds stage 2c+1; stage 2c+2 (if any) in flight
        if (c < 7) {
            asm volatile("s_waitcnt vmcnt(4)" ::: "memory");
        } else {
            asm volatile("s_waitcnt vmcnt(0)" ::: "memory"); // last stage: drain
        }
#pragma unroll
        for (int i = 0; i < 4; ++i) {
            const float4 v  = ((const float4*)buf[w][1])[i * 64 + lane];
            const int4   id = id4[4 + i];
            atomicMax((unsigned*)&pw[(id.x << 2) + g4], __float_as_uint(fmaxf(v.x, 0.f)));
            atomicMax((unsigned*)&pw[(id.y << 2) + g4], __float_as_uint(fmaxf(v.y, 0.f)));
            atomicMax((unsigned*)&pw[(id.z << 2) + g4], __float_as_uint(fmaxf(v.z, 0.f)));
            atomicMax((unsigned*)&pw[(id.w << 2) + g4], __float_as_uint(fmaxf(v.w, 0.f)));
        }
        asm volatile("s_waitcnt lgkmcnt(4)" ::: "memory");   // buf1 reads retired
        if (c < 7)
            stage4(esrc + HW + SUB, buf[w][1], lane);        // stage 2c+3

        // ---- merge channel c (LDS-only: vmcnt untouched, prefetch keeps flying)
        asm volatile("s_waitcnt lgkmcnt(0)" ::: "memory");   // atomics drained
        if (lane < NID) {
            const float4 m4 = pw4[lane + 1];
            res[w][lane][c] = fmaxf(fmaxf(m4.x, m4.y), fmaxf(m4.z, m4.w));
        }
        if (lane < 33) pw4[lane] = z4;   // re-zero; same-wave DS pipe is in-order
    }

    // epilogue: one global atomic per (id, channel)
    asm volatile("s_waitcnt lgkmcnt(0)" ::: "memory");
    if (lane < NID) {
        const float4 r0 = *(const float4*)&res[w][lane][0];
        const float4 r1 = *(const float4*)&res[w][lane][4];
        float* vd = vectors + ((size_t)b * NID + lane) * FCH + w * 8;
        if (r0.x > 0.f) atomicMax((unsigned*)&vd[0], __float_as_uint(r0.x));
        if (r0.y > 0.f) atomicMax((unsigned*)&vd[1], __float_as_uint(r0.y));
        if (r0.z > 0.f) atomicMax((unsigned*)&vd[2], __float_as_uint(r0.z));
        if (r0.w > 0.f) atomicMax((unsigned*)&vd[3], __float_as_uint(r0.w));
        if (r1.x > 0.f) atomicMax((unsigned*)&vd[4], __float_as_uint(r1.x));
        if (r1.y > 0.f) atomicMax((unsigned*)&vd[5], __float_as_uint(r1.y));
        if (r1.z > 0.f) atomicMax((unsigned*)&vd[6], __float_as_uint(r1.z));
        if (r1.w > 0.f) atomicMax((unsigned*)&vd[7], __float_as_uint(r1.w));
    }
}

// ---------------------------------------------------------------------------
// Kernel 2: collapsed pairwise MLP (no nonlinearity between layers):
// out[b,i,j,c] = sigmoid(v_i·A[:,c] + v_j·B[:,c] + cc[c]),
// A = w1[:64]@w2, B = w1[64:]@w2, cc = b1@w2 + b2.
// connections[b, c, j, i] = out[b, i, j, c].      (~5 us, unchanged)
// ---------------------------------------------------------------------------
__global__ __launch_bounds__(256) void conn_kernel(
    const float* __restrict__ vectors,  // [B, NID, F]
    const float* __restrict__ w1,       // [128, 32]
    const float* __restrict__ b1,       // [32]
    const float* __restrict__ w2,       // [32, 4]
    const float* __restrict__ b2,       // [4]
    float*       __restrict__ out)      // [B, 4, NID, NID]
{
    const int b   = blockIdx.x;
    const int tid = threadIdx.x;

    __shared__ float v[NID][FCH];
    __shared__ float A[FCH][4], Bm[FCH][4];
    __shared__ float s[NID][4], t[NID][4];
    __shared__ float cc[4];

    for (int i = tid; i < NID * FCH; i += 256)
        ((float*)v)[i] = vectors[(size_t)b * NID * FCH + i];

    {
        const int k = tid >> 2, c = tid & 3;
        float a = 0.0f, bb = 0.0f;
#pragma unroll
        for (int h = 0; h < 32; ++h) {
            const float w2v = w2[h * 4 + c];
            a  += w1[k * 32 + h]        * w2v;
            bb += w1[(k + 64) * 32 + h] * w2v;
        }
        A[k][c]  = a;
        Bm[k][c] = bb;
        if (tid < 4) {
            float x = b2[tid];
#pragma unroll
            for (int h = 0; h < 32; ++h) x += b1[h] * w2[h * 4 + tid];
            cc[tid] = x;
        }
    }
    __syncthreads();

    if (tid < 128) {
        const int i = tid >> 2, c = tid & 3;
        float a = 0.0f;
#pragma unroll
        for (int f = 0; f < FCH; ++f) a += v[i][f] * A[f][c];
        s[i][c] = a;
    } else {
        const int j = (tid - 128) >> 2, c = tid & 3;
        float a = 0.0f;
#pragma unroll
        for (int f = 0; f < FCH; ++f) a += v[j][f] * Bm[f][c];
        t[j][c] = a;
    }
    __syncthreads();

    for (int o = tid; o < 4 * NID * NID; o += 256) {
        const int i = o & 31;
        const int j = (o >> 5) & 31;
        const int c = o >> 10;
        const float x = s[i][c] + t[j][c] + cc[c];
        out[(((size_t)b * 4 + c) * NID + j) * NID + i] = 1.0f / (1.0f + expf(-x));
    }
}

extern "C" void kernel_launch(void* const* d_in, const int* in_sizes, int n_in,
                              void* d_out, int out_size, void* d_ws, size_t ws_size,
                              hipStream_t stream) {
    const float* encoded = (const float*)d_in[0];
    const int*   masks   = (const int*)d_in[1];
    const float* w1      = (const float*)d_in[2];
    const float* b1      = (const float*)d_in[3];
    const float* w2      = (const float*)d_in[4];
    const float* b2      = (const float*)d_in[5];
    float* out = (float*)d_out;

    float* vectors     = out;                        // NB*NID*FCH = 16384 floats
    float* connections = out + NB * NID * FCH;       // NB*4*NID*NID = 32768 floats

    // vectors must start at 0 (uint-monotone atomicMax; absent id -> 0)
    hipMemsetAsync(vectors, 0, (size_t)NB * NID * FCH * sizeof(float), stream);

    segmax_kernel<<<dim3(HW / CHUNK, NB), 512, 0, stream>>>(encoded, masks, vectors);
    conn_kernel<<<NB, 256, 0, stream>>>(vectors, w1, b1, w2, b2, connections);
}

// Round 4
// 714.920 us; speedup vs baseline: 1.0776x; 1.0714x over previous
//
#include <hip/hip_runtime.h>
#include <math.h>

#define HW    (512 * 512)
#define FCH   64
#define NB    8
#define NID   32
#define CHUNK 4096
#define ACC_STRIDE 33   // bank = (f + id-1) % 32 -> distinct ids hit distinct banks

// ---------------------------------------------------------------------------
// Kernel 1: per-instance segment max over encoded [B, F, H, W], ids in masks.
// REVERT to the round-0 structure (measured 713.27 us) after the glds arc
// (R2/R3) regressed +50 us and atomic-layout surgery (R1) was null.
//
// Model that fits all four rounds: this kernel is already HBM-bound
// (~128 KB/CU in flight from 32 waves x ~4 unrolled float4 loads), so
// segmax ~ 100 us; the rest of the 713-us window is harness traffic
// (2.1 GB workspace fill ~330 us + input re-poison + small resets).
// ---------------------------------------------------------------------------
__global__ __launch_bounds__(512) void segmax_kernel(
    const float* __restrict__ encoded,
    const int*   __restrict__ masks,
    float*       __restrict__ vectors)   // [B, NID, F], pre-zeroed
{
    const int b      = blockIdx.y;
    const int chunk0 = blockIdx.x * CHUNK;
    const int tid    = threadIdx.x;
    const int wave   = tid >> 6;
    const int lane   = tid & 63;

    __shared__ int   ids[CHUNK];              // 16 KB
    __shared__ float acc[FCH * ACC_STRIDE];   // 8.25 KB

    for (int i = tid; i < FCH * ACC_STRIDE; i += 512)
        acc[i] = 0.0f;

    {
        const int4* msrc = (const int4*)(masks + (size_t)b * HW + chunk0);
        int4* mdst = (int4*)ids;
        for (int i = tid; i < CHUNK / 4; i += 512)
            mdst[i] = msrc[i];
    }
    __syncthreads();

    const float* ebase = encoded + (size_t)b * FCH * HW + chunk0;

    for (int k = 0; k < 8; ++k) {
        const int f = wave * 8 + k;
        const float4* src = (const float4*)(ebase + (size_t)f * HW);
        float* facc = acc + f * ACC_STRIDE;
#pragma unroll 4
        for (int it = 0; it < 16; ++it) {   // 16 x float4 per lane per channel
            const int idx = it * 64 + lane;
            float4 v  = src[idx];
            int4   id = ((const int4*)ids)[idx];
            if (id.x > 0 && v.x > 0.0f) atomicMax((unsigned*)&facc[id.x - 1], __float_as_uint(v.x));
            if (id.y > 0 && v.y > 0.0f) atomicMax((unsigned*)&facc[id.y - 1], __float_as_uint(v.y));
            if (id.z > 0 && v.z > 0.0f) atomicMax((unsigned*)&facc[id.z - 1], __float_as_uint(v.z));
            if (id.w > 0 && v.w > 0.0f) atomicMax((unsigned*)&facc[id.w - 1], __float_as_uint(v.w));
        }
    }
    __syncthreads();

    for (int e = tid; e < FCH * NID; e += 512) {
        const int f = e >> 5;   // 0..63
        const int n = e & 31;   // id-1
        const float m = acc[f * ACC_STRIDE + n];
        if (m > 0.0f)
            atomicMax((unsigned*)&vectors[((size_t)b * NID + n) * FCH + f],
                      __float_as_uint(m));
    }
}

// ---------------------------------------------------------------------------
// Kernel 2: collapsed pairwise MLP (no nonlinearity between layers):
// out[b,i,j,c] = sigmoid(v_i·A[:,c] + v_j·B[:,c] + cc[c]),
// A = w1[:64]@w2, B = w1[64:]@w2, cc = b1@w2 + b2.
// connections[b, c, j, i] = out[b, i, j, c].
// ---------------------------------------------------------------------------
__global__ __launch_bounds__(256) void conn_kernel(
    const float* __restrict__ vectors,  // [B, NID, F]
    const float* __restrict__ w1,       // [128, 32]
    const float* __restrict__ b1,       // [32]
    const float* __restrict__ w2,       // [32, 4]
    const float* __restrict__ b2,       // [4]
    float*       __restrict__ out)      // [B, 4, NID, NID]
{
    const int b   = blockIdx.x;
    const int tid = threadIdx.x;

    __shared__ float v[NID][FCH];
    __shared__ float A[FCH][4], Bm[FCH][4];
    __shared__ float s[NID][4], t[NID][4];
    __shared__ float cc[4];

    for (int i = tid; i < NID * FCH; i += 256)
        ((float*)v)[i] = vectors[(size_t)b * NID * FCH + i];

    {
        const int k = tid >> 2, c = tid & 3;
        float a = 0.0f, bb = 0.0f;
#pragma unroll
        for (int h = 0; h < 32; ++h) {
            const float w2v = w2[h * 4 + c];
            a  += w1[k * 32 + h]        * w2v;
            bb += w1[(k + 64) * 32 + h] * w2v;
        }
        A[k][c]  = a;
        Bm[k][c] = bb;
        if (tid < 4) {
            float x = b2[tid];
#pragma unroll
            for (int h = 0; h < 32; ++h) x += b1[h] * w2[h * 4 + tid];
            cc[tid] = x;
        }
    }
    __syncthreads();

    if (tid < 128) {
        const int i = tid >> 2, c = tid & 3;
        float a = 0.0f;
#pragma unroll
        for (int f = 0; f < FCH; ++f) a += v[i][f] * A[f][c];
        s[i][c] = a;
    } else {
        const int j = (tid - 128) >> 2, c = tid & 3;
        float a = 0.0f;
#pragma unroll
        for (int f = 0; f < FCH; ++f) a += v[j][f] * Bm[f][c];
        t[j][c] = a;
    }
    __syncthreads();

    for (int o = tid; o < 4 * NID * NID; o += 256) {
        const int i = o & 31;
        const int j = (o >> 5) & 31;
        const int c = o >> 10;
        const float x = s[i][c] + t[j][c] + cc[c];
        out[(((size_t)b * 4 + c) * NID + j) * NID + i] = 1.0f / (1.0f + expf(-x));
    }
}

extern "C" void kernel_launch(void* const* d_in, const int* in_sizes, int n_in,
                              void* d_out, int out_size, void* d_ws, size_t ws_size,
                              hipStream_t stream) {
    const float* encoded = (const float*)d_in[0];
    const int*   masks   = (const int*)d_in[1];
    const float* w1      = (const float*)d_in[2];
    const float* b1      = (const float*)d_in[3];
    const float* w2      = (const float*)d_in[4];
    const float* b2      = (const float*)d_in[5];
    float* out = (float*)d_out;

    float* vectors     = out;                        // NB*NID*FCH = 16384 floats
    float* connections = out + NB * NID * FCH;       // NB*4*NID*NID = 32768 floats

    // vectors must start at 0 (atomicMax accumulation; absent id -> 0)
    hipMemsetAsync(vectors, 0, (size_t)NB * NID * FCH * sizeof(float), stream);

    segmax_kernel<<<dim3(HW / CHUNK, NB), 512, 0, stream>>>(encoded, masks, vectors);
    conn_kernel<<<NB, 256, 0, stream>>>(vectors, w1, b1, w2, b2, connections);
}